// Round 15
// baseline (453.023 us; speedup 1.0000x reference)
//
#include <hip/hip_runtime.h>

#define N_NODES 20000
#define HALF (N_NODES / 2)           // src phase boundary
#define HID 64
#define NSTEPS 6
#define NSLICE 8
#define SLICE_SZ (N_NODES / NSLICE)  // 2500
#define SLICE_BINS (2 * SLICE_SZ)    // 5000: (dst, src-half) bins, half-major
#define SUBB 256                     // sub-chunks per slice (phase 2)
#define NBLK (NSLICE * SUBB)         // 2048 blocks for hist/scatter
#define TBLK ((N_NODES + 63) / 64)   // 313 transpose blocks (fused into scatter)
#define NB1 2048                     // blocks for count/bucket phase
#define CBLK ((N_NODES + 255) / 256) // 79 colscan/scan2 blocks
#define MAGIC 13422                  // floor(d*13422 / 2^25) == d/2500 for d < 20000

typedef float f4_t __attribute__((ext_vector_type(4)));
typedef unsigned u4_t __attribute__((ext_vector_type(4)));

union U16H { unsigned short u; _Float16 h; };

__device__ __forceinline__ _Float16 us_as_h(unsigned short s) { U16H u; u.u = s; return u.h; }
__device__ __forceinline__ unsigned short h_as_us(_Float16 h) { U16H u; u.h = h; return u.u; }

__device__ __forceinline__ int slice_of(int d) {
    return (int)(((unsigned)d * (unsigned)MAGIC) >> 25);
}
__device__ __forceinline__ float softplusf_(float x) {
    return (x > 0.f) ? (x + log1pf(expf(-x))) : log1pf(expf(x));
}
__device__ __forceinline__ float sigmoidf_(float x) {
    return 1.f / (1.f + expf(-x));
}

// ---------------- P0: per-(block,slice) edge counts + zero eg groups ----------------
__global__ __launch_bounds__(256) void count8_kernel(const int* __restrict__ edst,
                                                     int* __restrict__ gcnt, int TE,
                                                     u4_t* __restrict__ egq, long long egq_n) {
    // fused: zero the grouped-entry buffer (pad slots must read {src=0,coef=0})
    u4_t z = {0u, 0u, 0u, 0u};
    for (long long i = (long long)blockIdx.x * 256 + threadIdx.x; i < egq_n;
         i += (long long)NB1 * 256)
        __builtin_nontemporal_store(z, egq + i);

    __shared__ int lh[8];
    int bk = blockIdx.x;
    int lane = threadIdx.x & 63;
    if (threadIdx.x < 8) lh[threadIdx.x] = 0;
    __syncthreads();
    int chunk = ((TE + NB1 - 1) / NB1 + 255) & ~255;
    int lo = bk * chunk;
    int hi = min(lo + chunk, TE);
    int my = 0;
    for (int ii = 0; ii < chunk; ii += 256) {
        int i = lo + ii + (int)threadIdx.x;
        bool act = i < hi;
        int s = -1;
        if (act) s = slice_of(__builtin_nontemporal_load(edst + i));
#pragma unroll
        for (int q = 0; q < 8; ++q) {
            unsigned long long b = __ballot(s == q);
            if (lane == q) my += (int)__popcll(b);
        }
    }
    if (lane < 8) atomicAdd(&lh[lane], my);
    __syncthreads();
    if (threadIdx.x < 8) gcnt[bk * 8 + threadIdx.x] = lh[threadIdx.x];
}

// ---------------- P0b: scan gcnt -> blkoff + bbase[9]; fused prep constants ----------------
__global__ __launch_bounds__(256) void scan8_kernel(const int* __restrict__ gcnt,
                                                    int* __restrict__ blkoff,
                                                    int* __restrict__ bbase,
                                                    const float* __restrict__ g_logits,
                                                    const float* __restrict__ alpha_logits,
                                                    const int* __restrict__ cell_idx,
                                                    const float* __restrict__ cell_emb,
                                                    const float* __restrict__ W2,
                                                    const float* __restrict__ b2,
                                                    float* __restrict__ gsign,
                                                    float* __restrict__ alph,
                                                    float* __restrict__ cell_dot) {
    __shared__ int psum[8][33];
    int tid = threadIdx.x;
    int s = tid >> 5, g = tid & 31;
    const int per = NB1 / 32;  // 64
    int sum = 0;
    for (int b = g * per; b < (g + 1) * per; ++b) sum += gcnt[b * 8 + s];
    psum[s][g] = sum;
    __syncthreads();
    if (tid < 8) {
        int run = 0;
        for (int i = 0; i < 32; ++i) { int v = psum[tid][i]; psum[tid][i] = run; run += v; }
        psum[tid][32] = run;
    }
    __syncthreads();
    int run = psum[s][g];
    for (int b = g * per; b < (g + 1) * per; ++b) {
        blkoff[b * 8 + s] = run;
        run += gcnt[b * 8 + s];
    }
    if (tid == 0) {
        int acc = 0;
        bbase[0] = 0;
        for (int q = 0; q < 8; ++q) { acc += psum[q][32]; bbase[q + 1] = acc; }
    }
    // fused prep (independent outputs)
    if (tid < 64) {
        if (tid < 6) gsign[tid] = ((tid & 1) ? -1.f : 1.f) * softplusf_(g_logits[tid]);
        if (tid < NSTEPS) alph[tid] = sigmoidf_(alpha_logits[tid]);
        int ci = cell_idx[tid];
        float acc = b2[0];
        for (int hh = 0; hh < HID; ++hh) acc = fmaf(cell_emb[ci * HID + hh], W2[hh], acc);
        cell_dot[tid] = acc;
    }
}

// ---------------- P1: bucket edges by slice; pack {src | bin<<16, coef_f32} ----------------
// bin = dl + (src >= HALF ? SLICE_SZ : 0)  — half-major (dst, src-half) sort key
__global__ __launch_bounds__(256) void bucket_kernel(const int* __restrict__ esrc,
                                                     const int* __restrict__ edst,
                                                     const float* __restrict__ eval,
                                                     const float* __restrict__ gsign,
                                                     const int* __restrict__ blkoff,
                                                     const int* __restrict__ bbase,
                                                     int2* __restrict__ bucket,
                                                     int E, int TE) {
    __shared__ int lcur[8];
    int bk = blockIdx.x;
    int lane = threadIdx.x & 63;
    if (threadIdx.x < 8) lcur[threadIdx.x] = bbase[threadIdx.x] + blkoff[bk * 8 + threadIdx.x];
    __syncthreads();
    int chunk = ((TE + NB1 - 1) / NB1 + 255) & ~255;
    int lo = bk * chunk;
    int hi = min(lo + chunk, TE);
    for (int ii = 0; ii < chunk; ii += 256) {
        int i = lo + ii + (int)threadIdx.x;
        bool act = i < hi;
        int s = -1, meta = 0, cb = 0;
        if (act) {
            int d  = __builtin_nontemporal_load(edst + i);
            int sv = __builtin_nontemporal_load(esrc + i);
            float ev = __builtin_nontemporal_load(eval + i);
            s = slice_of(d);
            int dl = d - s * SLICE_SZ;
            int bin = dl + ((sv >= HALF) ? SLICE_SZ : 0);
            meta = sv | (bin << 16);
            int r = (i >= E) + (i >= 2 * E) + (i >= 3 * E) + (i >= 4 * E) + (i >= 5 * E);
            cb = __float_as_int(gsign[r] * ev);
        }
        int pos = 0;
#pragma unroll
        for (int q = 0; q < 8; ++q) {
            unsigned long long b = __ballot(s == q);
            if (b) {
                int leader = (int)__ffsll(b) - 1;
                int base = 0;
                if (lane == leader) base = atomicAdd(&lcur[q], (int)__popcll(b));
                base = __shfl(base, leader);
                if (s == q) pos = base + (int)__popcll(b & ((1ull << lane) - 1ull));
            }
        }
        if (act) bucket[pos] = make_int2(meta, cb);
    }
}

// ---------------- P2: per-(slice,sub) LDS histogram (5000 bins) from the bucket ----------------
__global__ __launch_bounds__(256) void hist2db_kernel(const int2* __restrict__ bucket,
                                                      const int* __restrict__ bbase,
                                                      int* __restrict__ blkcnt) {
    __shared__ int lh[SLICE_BINS];  // 20 KB
    int bk = blockIdx.x;
    int slice = bk & (NSLICE - 1);
    int sub = bk >> 3;
    for (int b = threadIdx.x; b < SLICE_BINS; b += 256) lh[b] = 0;
    __syncthreads();
    int lo = bbase[slice];
    int total = bbase[slice + 1] - lo;
    int chunk = ((total + SUBB - 1) / SUBB + 255) & ~255;
    int beg = lo + sub * chunk;
    int end = min(beg + chunk, lo + total);
    const int* mp = (const int*)bucket;
    for (int i = beg + (int)threadIdx.x; i < end; i += 256) {
        int meta = __builtin_nontemporal_load(mp + 2 * (size_t)i);
        atomicAdd(&lh[((unsigned)meta) >> 16], 1);
    }
    __syncthreads();
    int* out = blkcnt + (size_t)(slice * SUBB + sub) * SLICE_BINS;
    for (int b = threadIdx.x; b < SLICE_BINS; b += 256) out[b] = lh[b];
}

// ---------------- P3a: per-bin prefix across sub-blocks; counts + h0cnt + blksum ----------------
__global__ __launch_bounds__(256) void colscan_kernel(int* __restrict__ blkcnt,
                                                      int* __restrict__ counts,
                                                      int* __restrict__ h0cnt,
                                                      int* __restrict__ blksum) {
    int n = blockIdx.x * 256 + threadIdx.x;
    int tot = 0;
    if (n < N_NODES) {
        int slice = n / SLICE_SZ, dl = n % SLICE_SZ;
        size_t base0 = (size_t)slice * SUBB * SLICE_BINS + dl;  // half-0 bin
        size_t base1 = base0 + SLICE_SZ;                        // half-1 bin
        int run0 = 0, run1 = 0;
#pragma unroll 4
        for (int s = 0; s < SUBB; ++s) {
            size_t i0 = base0 + (size_t)s * SLICE_BINS;
            size_t i1 = base1 + (size_t)s * SLICE_BINS;
            int t0 = blkcnt[i0], t1 = blkcnt[i1];
            blkcnt[i0] = run0;
            blkcnt[i1] = run1;
            run0 += t0;
            run1 += t1;
        }
        counts[n] = run0 + run1;
        h0cnt[n] = run0;
        tot = run0 + run1;
    }
    // fused: block sum of padded group counts (groups of 4) -> blksum[blockIdx.x]
    int g = (n < N_NODES) ? ((tot + 3) >> 2) : 0;
#pragma unroll
    for (int st = 1; st < 64; st <<= 1) g += __shfl_xor(g, st, 64);
    __shared__ int wsum[4];
    if ((threadIdx.x & 63) == 0) wsum[threadIdx.x >> 6] = g;
    __syncthreads();
    if (threadIdx.x == 0) blksum[blockIdx.x] = wsum[0] + wsum[1] + wsum[2] + wsum[3];
}

// ---------------- P3b: parallel scan -> grp_ptr (79 blocks, no serial chain) ----------------
__global__ __launch_bounds__(256) void scan2_kernel(const int* __restrict__ counts,
                                                    const int* __restrict__ blksum,
                                                    int* __restrict__ grp_ptr, int n) {
    int b = blockIdx.x;
    int tid = threadIdx.x, lane = tid & 63, wid = tid >> 6;
    int i = b * 256 + tid;
    int v = (i < n) ? ((counts[i] + 3) >> 2) : 0;
    int x = v;
#pragma unroll
    for (int st = 1; st < 64; st <<= 1) {
        int t = __shfl_up(x, st, 64);
        if (lane >= st) x += t;
    }
    __shared__ int wsum[4];
    if (lane == 63) wsum[wid] = x;
    // global offset: sum of blksum[l < b], redundant per wave (CBLK=79 < 128)
    int s = ((lane < b) ? blksum[lane] : 0) +
            ((lane + 64 < b) ? blksum[lane + 64] : 0);
#pragma unroll
    for (int st = 1; st < 64; st <<= 1) s += __shfl_xor(s, st, 64);
    __syncthreads();
    int woff = s;
    if (wid > 0) woff += wsum[0];
    if (wid > 1) woff += wsum[1];
    if (wid > 2) woff += wsum[2];
    int off = woff + x - v;  // exclusive
    if (i < n) grp_ptr[i] = off;
    if (i == n - 1) grp_ptr[n] = off + v;
}

// ---------------- P4: placement into 4-edge groups; fused u-transpose ----------------
// Row layout: [half-0 entries][half-1 entries], padded to ×4. Pad slots stay 0.
// u_t must NOT alias bucket (transpose blocks run concurrently with scatter).
__global__ __launch_bounds__(256) void scatter2b_kernel(const int2* __restrict__ bucket,
                                                        const int* __restrict__ bbase,
                                                        const int* __restrict__ grp_ptr,
                                                        const int* __restrict__ h0cnt,
                                                        const int* __restrict__ blkcnt,
                                                        unsigned* __restrict__ eg,
                                                        const float* __restrict__ u_raw,
                                                        float* __restrict__ u_t) {
    __shared__ float smem[SLICE_BINS + 16];  // union: lbase (20 KB) | transpose tile
    int bk = blockIdx.x;
    if (bk >= NBLK) {
        // --- transpose section: u_raw [64, N] -> u_t [N, 64] ---
        float(*tile)[65] = (float(*)[65])smem;
        int c0 = (bk - NBLK) * 64;
        int tx = threadIdx.x & 63, ty = threadIdx.x >> 6;
#pragma unroll
        for (int i = 0; i < 16; ++i) {
            int c = c0 + tx;
            tile[ty + i * 4][tx] = (c < N_NODES) ? u_raw[(size_t)(ty + i * 4) * N_NODES + c] : 0.f;
        }
        __syncthreads();
#pragma unroll
        for (int i = 0; i < 16; ++i) {
            int c = c0 + ty + i * 4;
            if (c < N_NODES) u_t[(size_t)c * 64 + tx] = tile[tx][ty + i * 4];
        }
        return;
    }
    int* lbase = (int*)smem;
    int slice = bk & (NSLICE - 1);
    int sub = bk >> 3;
    int lo_n = slice * SLICE_SZ;
    const int* boff = blkcnt + (size_t)(slice * SUBB + sub) * SLICE_BINS;
    for (int b = threadIdx.x; b < SLICE_BINS; b += 256) {
        int dl = (b < SLICE_SZ) ? b : (b - SLICE_SZ);
        int node = lo_n + dl;
        int h0 = (b < SLICE_SZ) ? 0 : h0cnt[node];
        lbase[b] = grp_ptr[node] * 4 + h0 + boff[b];
    }
    __syncthreads();
    int lo = bbase[slice];
    int total = bbase[slice + 1] - lo;
    int chunk = ((total + SUBB - 1) / SUBB + 255) & ~255;
    int beg = lo + sub * chunk;
    int end = min(beg + chunk, lo + total);
    for (int i = beg + (int)threadIdx.x; i < end; i += 256) {
        long long rec = __builtin_nontemporal_load((const long long*)bucket + i);
        int meta = (int)rec;
        float cf = __int_as_float((int)(rec >> 32));
        int pos = atomicAdd(&lbase[((unsigned)meta) >> 16], 1);
        eg[pos] = (unsigned)(meta & 0xFFFF) | ((unsigned)h_as_us((_Float16)cf) << 16);
    }
}

// ---------------- propagation step: fp32 h, 4 edges/gather, 2-deep pipeline ----------------
// Wave = 1 node. Lane L: edge slot (L>>4) of each group, batch quartet (L&15)*4.
// Row entries are src-half sorted: first ~half of each row touches only
// h[0..HALF) (2.56 MB, L2-resident), then h[HALF..N) — no L2 thrash.
__global__ __launch_bounds__(256) void step_kernel(const float* __restrict__ h_in,
                                                   const float* __restrict__ h0,
                                                   float* __restrict__ h_out,
                                                   const int* __restrict__ grp_ptr,
                                                   const unsigned* __restrict__ eg,
                                                   const float* __restrict__ alph,
                                                   int k) {
    int lane = threadIdx.x & 63;
    int node = blockIdx.x * 4 + (threadIdx.x >> 6);
    if (node >= N_NODES) return;
    int gb = __builtin_amdgcn_readfirstlane(grp_ptr[node]);
    int ge = __builtin_amdgcn_readfirstlane(grp_ptr[node + 1]);
    int sub4 = lane >> 4;
    const float* hbase = h_in + (lane & 15) * 4;
    const unsigned* ep = eg + sub4;
    float acc[4] = {0.f, 0.f, 0.f, 0.f};
    int g = gb;
    int pairs = (ge - g) >> 1;
    if (pairs >= 2) {
        size_t b0 = (size_t)g * 4;
        unsigned ea0 = ep[b0], ea1 = ep[b0 + 4];
        f4_t va0 = *(const f4_t*)(hbase + (ea0 & 0xFFFFu) * 64);
        f4_t va1 = *(const f4_t*)(hbase + (ea1 & 0xFFFFu) * 64);
        unsigned eb0 = ep[b0 + 8], eb1 = ep[b0 + 12];
        int p = 0;
        for (; p + 2 < pairs; ++p) {
            f4_t vb0 = *(const f4_t*)(hbase + (eb0 & 0xFFFFu) * 64);
            f4_t vb1 = *(const f4_t*)(hbase + (eb1 & 0xFFFFu) * 64);
            size_t bn = (size_t)(g + 2 * (p + 2)) * 4;
            unsigned ec0 = ep[bn], ec1 = ep[bn + 4];
            float c0 = (float)us_as_h((unsigned short)(ea0 >> 16));
            float c1 = (float)us_as_h((unsigned short)(ea1 >> 16));
#pragma unroll
            for (int j = 0; j < 4; ++j) acc[j] = fmaf(va0[j], c0, acc[j]);
#pragma unroll
            for (int j = 0; j < 4; ++j) acc[j] = fmaf(va1[j], c1, acc[j]);
            ea0 = eb0; ea1 = eb1; eb0 = ec0; eb1 = ec1;
            va0 = vb0; va1 = vb1;
        }
        // drain: two pairs remain — (ea/va ready) and (eb entries loaded)
        f4_t vb0 = *(const f4_t*)(hbase + (eb0 & 0xFFFFu) * 64);
        f4_t vb1 = *(const f4_t*)(hbase + (eb1 & 0xFFFFu) * 64);
        float c0 = (float)us_as_h((unsigned short)(ea0 >> 16));
        float c1 = (float)us_as_h((unsigned short)(ea1 >> 16));
        float c2 = (float)us_as_h((unsigned short)(eb0 >> 16));
        float c3 = (float)us_as_h((unsigned short)(eb1 >> 16));
#pragma unroll
        for (int j = 0; j < 4; ++j) acc[j] = fmaf(va0[j], c0, acc[j]);
#pragma unroll
        for (int j = 0; j < 4; ++j) acc[j] = fmaf(va1[j], c1, acc[j]);
#pragma unroll
        for (int j = 0; j < 4; ++j) acc[j] = fmaf(vb0[j], c2, acc[j]);
#pragma unroll
        for (int j = 0; j < 4; ++j) acc[j] = fmaf(vb1[j], c3, acc[j]);
        g += 2 * pairs;
    }
    for (; g < ge; ++g) {
        unsigned e = ep[(size_t)g * 4];
        f4_t v = *(const f4_t*)(hbase + (e & 0xFFFFu) * 64);
        float c = (float)us_as_h((unsigned short)(e >> 16));
#pragma unroll
        for (int j = 0; j < 4; ++j) acc[j] = fmaf(v[j], c, acc[j]);
    }
    // reduce edge slots: lanes {q, q+16, q+32, q+48} share a batch quartet
#pragma unroll
    for (int st = 16; st < 64; st <<= 1) {
#pragma unroll
        for (int j = 0; j < 4; ++j) acc[j] += __shfl_xor(acc[j], st, 64);
    }
    if (lane < 16) {
        float a = alph[k];
        int base = node * 64 + lane * 4;
        float4 h0v = *(const float4*)(h0 + base);
        float om = 1.f - a;
        float4 r;
        r.x = fmaf(a, h0v.x, om * acc[0]);
        r.y = fmaf(a, h0v.y, om * acc[1]);
        r.z = fmaf(a, h0v.z, om * acc[2]);
        r.w = fmaf(a, h0v.w, om * acc[3]);
        *(float4*)(h_out + base) = r;
    }
}

// ---------------- decode (fused LDS transpose of h_final [N,64]) ----------------
__global__ __launch_bounds__(256) void decode_kernel(float* __restrict__ y,
                                                     const float* __restrict__ ctl,
                                                     const float* __restrict__ u,
                                                     const float* __restrict__ hF,
                                                     const float* __restrict__ W1,
                                                     const float* __restrict__ b1,
                                                     const float* __restrict__ W2,
                                                     const float* __restrict__ cell_dot) {
    __shared__ float tile[64][65];
    __shared__ float4 pack[HID];
    __shared__ float w2s[HID];
    __shared__ float cds[64];
    if (threadIdx.x < HID) {
        int hh = threadIdx.x;
        pack[hh] = make_float4(W1[0 * HID + hh], W1[1 * HID + hh], W1[2 * HID + hh], b1[hh]);
        w2s[hh] = W2[hh];
        cds[hh] = cell_dot[hh];
    }
    int n0 = blockIdx.x * 64;
    int tx = threadIdx.x & 63, ty = threadIdx.x >> 6;
#pragma unroll
    for (int i = 0; i < 16; ++i) {
        int n = n0 + ty + i * 4;
        tile[ty + i * 4][tx] = (n < N_NODES) ? hF[(size_t)n * 64 + tx] : 0.f;
    }
    __syncthreads();
#pragma unroll
    for (int i = 0; i < 16; ++i) {
        int b = ty + i * 4;
        int n = n0 + tx;
        if (n < N_NODES) {
            size_t idx = (size_t)b * N_NODES + n;
            float xc = ctl[idx], xu = u[idx], xh = tile[tx][b];
            float acc = 0.f;
#pragma unroll 8
            for (int hh = 0; hh < HID; ++hh) {
                float4 p = pack[hh];
                float t = fmaf(xc, p.x, fmaf(xu, p.y, fmaf(xh, p.z, p.w)));
                t = fmaxf(t, 0.f);
                acc = fmaf(t, w2s[hh], acc);
            }
            y[idx] = acc + cds[b];
        }
    }
}

// ---------------- launch ----------------
extern "C" void kernel_launch(void* const* d_in, const int* in_sizes, int n_in,
                              void* d_out, int out_size, void* d_ws, size_t ws_size,
                              hipStream_t stream) {
    const float* ctl          = (const float*)d_in[0];
    const float* u_raw        = (const float*)d_in[1];
    const int*   cell_idx     = (const int*)d_in[2];
    const int*   edge_src     = (const int*)d_in[3];
    const int*   edge_dst     = (const int*)d_in[4];
    const float* edge_val     = (const float*)d_in[5];
    const float* g_logits     = (const float*)d_in[6];
    const float* alpha_logits = (const float*)d_in[7];
    const float* cell_emb     = (const float*)d_in[8];
    const float* W1           = (const float*)d_in[9];
    const float* b1           = (const float*)d_in[10];
    const float* W2           = (const float*)d_in[11];
    const float* b2           = (const float*)d_in[12];
    float* y = (float*)d_out;

    const int TE = in_sizes[3];   // 6 * E
    const int E  = TE / 6;
    const int NB = N_NODES * 64;  // h elements

    char* ws = (char*)d_ws;
    size_t off = 0;
    auto alloc = [&](size_t bytes) -> char* {
        char* p = ws + off;
        off += (bytes + 255) & ~(size_t)255;
        return p;
    };
    int* grp_ptr = (int*)alloc((N_NODES + 1) * sizeof(int));
    int* counts  = (int*)alloc(N_NODES * sizeof(int));
    int* h0cnt   = (int*)alloc(N_NODES * sizeof(int));
    int* blksum  = (int*)alloc(CBLK * sizeof(int));
    int* blkcnt  = (int*)alloc((size_t)NSLICE * SUBB * SLICE_BINS * sizeof(int));  // 41 MB
    int* gcnt    = (int*)alloc((size_t)NB1 * 8 * sizeof(int));
    int* blkoff  = (int*)alloc((size_t)NB1 * 8 * sizeof(int));
    int* bbase   = (int*)alloc(16 * sizeof(int));
    const size_t MAXG = (size_t)TE / 4 + N_NODES + 8;             // padded group bound
    unsigned* eg = (unsigned*)alloc(MAXG * 4 * sizeof(unsigned)); // 16 B/group
    // DISTINCT buffers (no aliasing)
    int2* bucket    = (int2*)alloc((size_t)TE * sizeof(int2));
    float* hA       = (float*)alloc((size_t)NB * sizeof(float));
    float* hB       = (float*)alloc((size_t)NB * sizeof(float));
    float* u_t      = (float*)alloc((size_t)NB * sizeof(float));
    float* gsign    = (float*)alloc(8 * sizeof(float));
    float* alph     = (float*)alloc(8 * sizeof(float));
    float* cell_dot = (float*)alloc(64 * sizeof(float));

    // 1. CSR build — edges read once, zero global atomics, XCD-local placement,
    //    (dst, src-half) sort key for L2-resident step phases
    count8_kernel<<<NB1, 256, 0, stream>>>(edge_dst, gcnt, TE,
                                           (u4_t*)eg, (long long)MAXG);
    scan8_kernel<<<1, 256, 0, stream>>>(gcnt, blkoff, bbase, g_logits, alpha_logits,
                                        cell_idx, cell_emb, W2, b2,
                                        gsign, alph, cell_dot);
    bucket_kernel<<<NB1, 256, 0, stream>>>(edge_src, edge_dst, edge_val, gsign,
                                           blkoff, bbase, bucket, E, TE);
    hist2db_kernel<<<NBLK, 256, 0, stream>>>(bucket, bbase, blkcnt);
    colscan_kernel<<<CBLK, 256, 0, stream>>>(blkcnt, counts, h0cnt, blksum);
    scan2_kernel<<<CBLK, 256, 0, stream>>>(counts, blksum, grp_ptr, N_NODES);
    // 2. placement + fused u transpose (u_t fp32 = h0 = step-0 input)
    scatter2b_kernel<<<NBLK + TBLK, 256, 0, stream>>>(bucket, bbase, grp_ptr, h0cnt,
                                                      blkcnt, eg, u_raw, u_t);

    // 3. 6 propagation steps: fp32 ping-pong
    const float* hin = u_t;
    float* hout = hA;
    for (int k = 0; k < NSTEPS; ++k) {
        hout = (k & 1) ? hB : hA;
        step_kernel<<<(N_NODES + 3) / 4, 256, 0, stream>>>(hin, u_t, hout, grp_ptr,
                                                           eg, alph, k);
        hin = hout;
    }

    // 4. decode (reads h_final [N,64] directly via LDS transpose)
    decode_kernel<<<TBLK, 256, 0, stream>>>(y, ctl, u_raw, hout, W1, b1, W2, cell_dot);
}

// Round 16
// 387.446 us; speedup vs baseline: 1.1693x; 1.1693x over previous
//
#include <hip/hip_runtime.h>

#define N_NODES 20000
#define HID 64
#define NSTEPS 6
#define NSLICE 8
#define SLICE_SZ (N_NODES / NSLICE)  // 2500
#define SUBB 256                     // sub-chunks per slice
#define NBLK (NSLICE * SUBB)         // 2048 blocks for hist/scatter
#define TBLK ((N_NODES + 63) / 64)   // 313 transpose blocks (fused into hist)
#define NB1 2048                     // blocks for count/bucket phase
#define CBLK ((N_NODES + 255) / 256) // 79 colscan/scan2 blocks
#define MAGIC 13422                  // floor(d*13422 / 2^25) == d/2500 for d < 20000

typedef _Float16 h8_t __attribute__((ext_vector_type(8)));
typedef unsigned u4_t __attribute__((ext_vector_type(4)));

union U16H { unsigned short u; _Float16 h; };
union U4H8 { uint4 u; _Float16 h[8]; };

__device__ __forceinline__ _Float16 us_as_h(unsigned short s) { U16H u; u.u = s; return u.h; }
__device__ __forceinline__ unsigned short h_as_us(_Float16 h) { U16H u; u.h = h; return u.u; }

__device__ __forceinline__ int slice_of(int d) {
    return (int)(((unsigned)d * (unsigned)MAGIC) >> 25);
}
__device__ __forceinline__ float softplusf_(float x) {
    return (x > 0.f) ? (x + log1pf(expf(-x))) : log1pf(expf(x));
}
__device__ __forceinline__ float sigmoidf_(float x) {
    return 1.f / (1.f + expf(-x));
}

// ---------------- P0: per-(block,slice) edge counts + zero eg groups ----------------
__global__ __launch_bounds__(256) void count8_kernel(const int* __restrict__ edst,
                                                     int* __restrict__ gcnt, int TE,
                                                     u4_t* __restrict__ egq, long long egq_n) {
    u4_t z = {0u, 0u, 0u, 0u};
    for (long long i = (long long)blockIdx.x * 256 + threadIdx.x; i < egq_n;
         i += (long long)NB1 * 256)
        __builtin_nontemporal_store(z, egq + i);

    __shared__ int lh[8];
    int bk = blockIdx.x;
    int lane = threadIdx.x & 63;
    if (threadIdx.x < 8) lh[threadIdx.x] = 0;
    __syncthreads();
    int chunk = ((TE + NB1 - 1) / NB1 + 255) & ~255;
    int lo = bk * chunk;
    int hi = min(lo + chunk, TE);
    int my = 0;
    for (int ii = 0; ii < chunk; ii += 256) {
        int i = lo + ii + (int)threadIdx.x;
        bool act = i < hi;
        int s = -1;
        if (act) s = slice_of(__builtin_nontemporal_load(edst + i));
#pragma unroll
        for (int q = 0; q < 8; ++q) {
            unsigned long long b = __ballot(s == q);
            if (lane == q) my += (int)__popcll(b);
        }
    }
    if (lane < 8) atomicAdd(&lh[lane], my);  // commutative int -> deterministic
    __syncthreads();
    if (threadIdx.x < 8) gcnt[bk * 8 + threadIdx.x] = lh[threadIdx.x];
}

// ---------------- P0b: scan gcnt -> blkoff + bbase[9]; fused prep constants ----------------
__global__ __launch_bounds__(256) void scan8_kernel(const int* __restrict__ gcnt,
                                                    int* __restrict__ blkoff,
                                                    int* __restrict__ bbase,
                                                    const float* __restrict__ g_logits,
                                                    const float* __restrict__ alpha_logits,
                                                    const int* __restrict__ cell_idx,
                                                    const float* __restrict__ cell_emb,
                                                    const float* __restrict__ W2,
                                                    const float* __restrict__ b2,
                                                    float* __restrict__ gsign,
                                                    float* __restrict__ alph,
                                                    float* __restrict__ cell_dot) {
    __shared__ int psum[8][33];
    int tid = threadIdx.x;
    int s = tid >> 5, g = tid & 31;
    const int per = NB1 / 32;  // 64
    int sum = 0;
    for (int b = g * per; b < (g + 1) * per; ++b) sum += gcnt[b * 8 + s];
    psum[s][g] = sum;
    __syncthreads();
    if (tid < 8) {
        int run = 0;
        for (int i = 0; i < 32; ++i) { int v = psum[tid][i]; psum[tid][i] = run; run += v; }
        psum[tid][32] = run;
    }
    __syncthreads();
    int run = psum[s][g];
    for (int b = g * per; b < (g + 1) * per; ++b) {
        blkoff[b * 8 + s] = run;
        run += gcnt[b * 8 + s];
    }
    if (tid == 0) {
        int acc = 0;
        bbase[0] = 0;
        for (int q = 0; q < 8; ++q) { acc += psum[q][32]; bbase[q + 1] = acc; }
    }
    if (tid < 64) {
        if (tid < 6) gsign[tid] = ((tid & 1) ? -1.f : 1.f) * softplusf_(g_logits[tid]);
        if (tid < NSTEPS) alph[tid] = sigmoidf_(alpha_logits[tid]);
        int ci = cell_idx[tid];
        float acc = b2[0];
        for (int hh = 0; hh < HID; ++hh) acc = fmaf(cell_emb[ci * HID + hh], W2[hh], acc);
        cell_dot[tid] = acc;
    }
}

// ---------------- P1: DETERMINISTIC bucket by slice; pack {src | dl<<16, coef_f32} ----------
// Placement order is a pure function of (block, iteration, wave, lane): per-wave
// slice counts go through LDS wcnt with barriers instead of a free-running cursor.
__global__ __launch_bounds__(256) void bucket_kernel(const int* __restrict__ esrc,
                                                     const int* __restrict__ edst,
                                                     const float* __restrict__ eval,
                                                     const float* __restrict__ gsign,
                                                     const int* __restrict__ blkoff,
                                                     const int* __restrict__ bbase,
                                                     int2* __restrict__ bucket,
                                                     int E, int TE) {
    __shared__ int lcur[8];
    __shared__ int wcnt[4][8];
    int tid = threadIdx.x;
    int bk = blockIdx.x;
    int lane = tid & 63, wid = tid >> 6;
    if (tid < 8) lcur[tid] = bbase[tid] + blkoff[bk * 8 + tid];
    int chunk = ((TE + NB1 - 1) / NB1 + 255) & ~255;
    int lo = bk * chunk;
    int hi = min(lo + chunk, TE);
    for (int ii = 0; ii < chunk; ii += 256) {
        __syncthreads();  // lcur/wcnt stable from previous iteration
        int i = lo + ii + tid;
        bool act = i < hi;
        int s = -1, meta = 0, cb = 0;
        if (act) {
            int d  = __builtin_nontemporal_load(edst + i);
            int sv = __builtin_nontemporal_load(esrc + i);
            float ev = __builtin_nontemporal_load(eval + i);
            s = slice_of(d);
            int dl = d - s * SLICE_SZ;
            meta = sv | (dl << 16);
            int r = (i >= E) + (i >= 2 * E) + (i >= 3 * E) + (i >= 4 * E) + (i >= 5 * E);
            cb = __float_as_int(gsign[r] * ev);
        }
        int within = 0, wavecnt = 0;
        unsigned long long below = (1ull << lane) - 1ull;
#pragma unroll
        for (int q = 0; q < 8; ++q) {
            unsigned long long b = __ballot(s == q);
            if (s == q) within = (int)__popcll(b & below);
            if (lane == q) wavecnt = (int)__popcll(b);
        }
        if (lane < 8) wcnt[wid][lane] = wavecnt;
        __syncthreads();  // wcnt visible
        int pos = 0, newcur = 0;
        if (act) {
            int off = lcur[s];
            if (wid > 0) off += wcnt[0][s];
            if (wid > 1) off += wcnt[1][s];
            if (wid > 2) off += wcnt[2][s];
            pos = off + within;
        }
        if (tid < 8)
            newcur = lcur[tid] + wcnt[0][tid] + wcnt[1][tid] + wcnt[2][tid] + wcnt[3][tid];
        __syncthreads();  // all lcur reads done
        if (tid < 8) lcur[tid] = newcur;
        if (act) bucket[pos] = make_int2(meta, cb);
    }
}

// ---------------- P2: per-(slice,sub) LDS histogram; fused u-transpose ----------------
__global__ __launch_bounds__(256) void hist2db_kernel(const int2* __restrict__ bucket,
                                                      const int* __restrict__ bbase,
                                                      int* __restrict__ blkcnt,
                                                      const float* __restrict__ u_raw,
                                                      float* __restrict__ u_t,
                                                      _Float16* __restrict__ uh) {
    __shared__ float smem[64 * 65];  // union: hist lh (10 KB) | transpose tile (16.6 KB)
    int bk = blockIdx.x;
    if (bk >= NBLK) {
        // --- transpose section: u_raw [64, N] -> u_t (fp32) + uh (f16), [N, 64] ---
        float(*tile)[65] = (float(*)[65])smem;
        int c0 = (bk - NBLK) * 64;
        int tx = threadIdx.x & 63, ty = threadIdx.x >> 6;
#pragma unroll
        for (int i = 0; i < 16; ++i) {
            int c = c0 + tx;
            tile[ty + i * 4][tx] = (c < N_NODES) ? u_raw[(size_t)(ty + i * 4) * N_NODES + c] : 0.f;
        }
        __syncthreads();
#pragma unroll
        for (int i = 0; i < 16; ++i) {
            int c = c0 + ty + i * 4;
            if (c < N_NODES) {
                float v = tile[tx][ty + i * 4];
                u_t[(size_t)c * 64 + tx] = v;
                uh[(size_t)c * 64 + tx] = (_Float16)v;
            }
        }
        return;
    }
    int* lh = (int*)smem;
    int slice = bk & (NSLICE - 1);
    int sub = bk >> 3;
    for (int b = threadIdx.x; b < SLICE_SZ; b += 256) lh[b] = 0;
    __syncthreads();
    int lo = bbase[slice];
    int total = bbase[slice + 1] - lo;
    int chunk = ((total + SUBB - 1) / SUBB + 255) & ~255;
    int beg = lo + sub * chunk;
    int end = min(beg + chunk, lo + total);
    const int* mp = (const int*)bucket;
    for (int i = beg + (int)threadIdx.x; i < end; i += 256) {
        int meta = __builtin_nontemporal_load(mp + 2 * (size_t)i);
        atomicAdd(&lh[((unsigned)meta) >> 16], 1);  // commutative int
    }
    __syncthreads();
    int* out = blkcnt + (size_t)(slice * SUBB + sub) * SLICE_SZ;
    for (int b = threadIdx.x; b < SLICE_SZ; b += 256) out[b] = lh[b];
}

// ---------------- P3a: per-bin prefix across sub-blocks + per-block group sums ----------------
__global__ __launch_bounds__(256) void colscan_kernel(int* __restrict__ blkcnt,
                                                      int* __restrict__ counts,
                                                      int* __restrict__ blksum) {
    int n = blockIdx.x * 256 + threadIdx.x;
    int run = 0;
    if (n < N_NODES) {
        int slice = n / SLICE_SZ, bin = n % SLICE_SZ;
        size_t base = (size_t)slice * SUBB * SLICE_SZ + bin;
#pragma unroll 8
        for (int s = 0; s < SUBB; ++s) {
            size_t idx = base + (size_t)s * SLICE_SZ;
            int t = blkcnt[idx];
            blkcnt[idx] = run;
            run += t;
        }
        counts[n] = run;
    }
    int g = (n < N_NODES) ? ((run + 7) >> 3) : 0;  // groups of 8
#pragma unroll
    for (int st = 1; st < 64; st <<= 1) g += __shfl_xor(g, st, 64);
    __shared__ int wsum[4];
    if ((threadIdx.x & 63) == 0) wsum[threadIdx.x >> 6] = g;
    __syncthreads();
    if (threadIdx.x == 0) blksum[blockIdx.x] = wsum[0] + wsum[1] + wsum[2] + wsum[3];
}

// ---------------- P3b: parallel scan -> grp_ptr (79 blocks) ----------------
__global__ __launch_bounds__(256) void scan2_kernel(const int* __restrict__ counts,
                                                    const int* __restrict__ blksum,
                                                    int* __restrict__ grp_ptr, int n) {
    int b = blockIdx.x;
    int tid = threadIdx.x, lane = tid & 63, wid = tid >> 6;
    int i = b * 256 + tid;
    int v = (i < n) ? ((counts[i] + 7) >> 3) : 0;
    int x = v;
#pragma unroll
    for (int st = 1; st < 64; st <<= 1) {
        int t = __shfl_up(x, st, 64);
        if (lane >= st) x += t;
    }
    __shared__ int wsum[4];
    if (lane == 63) wsum[wid] = x;
    int s = ((lane < b) ? blksum[lane] : 0) +
            ((lane + 64 < b) ? blksum[lane + 64] : 0);
#pragma unroll
    for (int st = 1; st < 64; st <<= 1) s += __shfl_xor(s, st, 64);
    __syncthreads();
    int woff = s;
    if (wid > 0) woff += wsum[0];
    if (wid > 1) woff += wsum[1];
    if (wid > 2) woff += wsum[2];
    int off = woff + x - v;
    if (i < n) grp_ptr[i] = off;
    if (i == n - 1) grp_ptr[n] = off + v;
}

// ---------------- P4: DETERMINISTIC placement into 8-edge groups ----------------
// One wave per block (no cross-wave cursor races). Intra-wave same-bin ranks via a
// 64-step shfl match loop; highest same-bin lane bumps the LDS cursor (non-atomic,
// distinct addresses). eg is bit-identical every launch -> f16 steps replay-stable.
__global__ __launch_bounds__(64) void scatter_det_kernel(const int2* __restrict__ bucket,
                                                         const int* __restrict__ bbase,
                                                         const int* __restrict__ grp_ptr,
                                                         const int* __restrict__ blkcnt,
                                                         unsigned* __restrict__ eg) {
    __shared__ int lbase[SLICE_SZ];
    int bk = blockIdx.x;
    int slice = bk & (NSLICE - 1);
    int sub = bk >> 3;
    int lane = threadIdx.x;
    int lo_n = slice * SLICE_SZ;
    const int* boff = blkcnt + (size_t)(slice * SUBB + sub) * SLICE_SZ;
    for (int b = lane; b < SLICE_SZ; b += 64)
        lbase[b] = grp_ptr[lo_n + b] * 8 + boff[b];
    __syncthreads();
    int lo = bbase[slice];
    int total = bbase[slice + 1] - lo;
    int chunk = ((total + SUBB - 1) / SUBB + 255) & ~255;
    int beg = lo + sub * chunk;
    int end = min(beg + chunk, lo + total);
    for (int i0 = beg; i0 < end; i0 += 64) {
        int i = i0 + lane;
        bool act = i < end;
        int meta = 0, cb = 0, bin = -1;
        if (act) {
            long long rec = *(const long long*)(bucket + i);
            meta = (int)rec;
            cb = (int)(rec >> 32);
            bin = (int)(((unsigned)meta) >> 16);
        }
        // deterministic rank among same-bin lanes (index order = lane order)
        int rank = 0, tot = 0;
        for (int l = 0; l < 64; ++l) {
            int ob = __shfl(bin, l, 64);
            bool same = (bin >= 0) && (ob == bin);
            rank += (same && l < lane) ? 1 : 0;
            tot  += same ? 1 : 0;
        }
        if (act) {
            int base = lbase[bin];
            int pos = base + rank;
            float cf = __uint_as_float((unsigned)cb);
            eg[pos] = (unsigned)(meta & 0xFFFF) | ((unsigned)h_as_us((_Float16)cf) << 16);
            if (rank == tot - 1) lbase[bin] = base + tot;  // single writer per bin
        }
        // single wave: LDS ops are program-ordered, no barrier needed
    }
}

// ---------------- propagation step: f16 h, 8 edges/gather, 2-deep pipeline ----------------
// Wave = 1 node. Lane L: edge slot (L>>3) of each group, batch octet (L&7)*8.
__global__ __launch_bounds__(256) void step_kernel(const _Float16* __restrict__ h_in,
                                                   const float* __restrict__ h0,
                                                   _Float16* __restrict__ h_out,
                                                   float* __restrict__ hF,
                                                   const int* __restrict__ grp_ptr,
                                                   const unsigned* __restrict__ eg,
                                                   const float* __restrict__ alph,
                                                   int k, int last) {
    int lane = threadIdx.x & 63;
    int node = blockIdx.x * 4 + (threadIdx.x >> 6);
    if (node >= N_NODES) return;
    int gb = __builtin_amdgcn_readfirstlane(grp_ptr[node]);
    int ge = __builtin_amdgcn_readfirstlane(grp_ptr[node + 1]);
    int sub8 = lane >> 3;
    const _Float16* hbase = h_in + (lane & 7) * 8;
    const unsigned* ep = eg + sub8;
    float acc[8] = {0.f, 0.f, 0.f, 0.f, 0.f, 0.f, 0.f, 0.f};
    int g = gb;
    int pairs = (ge - g) >> 1;
    if (pairs >= 2) {
        size_t b0 = (size_t)g * 8;
        unsigned ea0 = ep[b0], ea1 = ep[b0 + 8];
        h8_t va0 = *(const h8_t*)(hbase + (ea0 & 0xFFFFu) * 64);
        h8_t va1 = *(const h8_t*)(hbase + (ea1 & 0xFFFFu) * 64);
        unsigned eb0 = ep[b0 + 16], eb1 = ep[b0 + 24];
        int p = 0;
        for (; p + 2 < pairs; ++p) {
            h8_t vb0 = *(const h8_t*)(hbase + (eb0 & 0xFFFFu) * 64);
            h8_t vb1 = *(const h8_t*)(hbase + (eb1 & 0xFFFFu) * 64);
            size_t bn = (size_t)(g + 2 * (p + 2)) * 8;
            unsigned ec0 = ep[bn], ec1 = ep[bn + 8];
            float c0 = (float)us_as_h((unsigned short)(ea0 >> 16));
            float c1 = (float)us_as_h((unsigned short)(ea1 >> 16));
#pragma unroll
            for (int j = 0; j < 8; ++j) acc[j] = fmaf((float)va0[j], c0, acc[j]);
#pragma unroll
            for (int j = 0; j < 8; ++j) acc[j] = fmaf((float)va1[j], c1, acc[j]);
            ea0 = eb0; ea1 = eb1; eb0 = ec0; eb1 = ec1;
            va0 = vb0; va1 = vb1;
        }
        h8_t vb0 = *(const h8_t*)(hbase + (eb0 & 0xFFFFu) * 64);
        h8_t vb1 = *(const h8_t*)(hbase + (eb1 & 0xFFFFu) * 64);
        float c0 = (float)us_as_h((unsigned short)(ea0 >> 16));
        float c1 = (float)us_as_h((unsigned short)(ea1 >> 16));
        float c2 = (float)us_as_h((unsigned short)(eb0 >> 16));
        float c3 = (float)us_as_h((unsigned short)(eb1 >> 16));
#pragma unroll
        for (int j = 0; j < 8; ++j) acc[j] = fmaf((float)va0[j], c0, acc[j]);
#pragma unroll
        for (int j = 0; j < 8; ++j) acc[j] = fmaf((float)va1[j], c1, acc[j]);
#pragma unroll
        for (int j = 0; j < 8; ++j) acc[j] = fmaf((float)vb0[j], c2, acc[j]);
#pragma unroll
        for (int j = 0; j < 8; ++j) acc[j] = fmaf((float)vb1[j], c3, acc[j]);
        g += 2 * pairs;
    }
    for (; g < ge; ++g) {
        unsigned e = ep[(size_t)g * 8];
        h8_t v = *(const h8_t*)(hbase + (e & 0xFFFFu) * 64);
        float c = (float)us_as_h((unsigned short)(e >> 16));
#pragma unroll
        for (int j = 0; j < 8; ++j) acc[j] = fmaf((float)v[j], c, acc[j]);
    }
#pragma unroll
    for (int st = 8; st < 64; st <<= 1) {
#pragma unroll
        for (int j = 0; j < 8; ++j) acc[j] += __shfl_xor(acc[j], st, 64);
    }
    if (lane < 8) {
        float a = alph[k];
        int base = node * 64 + lane * 8;
        float4 h0a = *(const float4*)(h0 + base);
        float4 h0b = *(const float4*)(h0 + base + 4);
        float om = 1.f - a;
        float r0 = fmaf(a, h0a.x, om * acc[0]);
        float r1 = fmaf(a, h0a.y, om * acc[1]);
        float r2 = fmaf(a, h0a.z, om * acc[2]);
        float r3 = fmaf(a, h0a.w, om * acc[3]);
        float r4 = fmaf(a, h0b.x, om * acc[4]);
        float r5 = fmaf(a, h0b.y, om * acc[5]);
        float r6 = fmaf(a, h0b.z, om * acc[6]);
        float r7 = fmaf(a, h0b.w, om * acc[7]);
        if (last) {
            *(float4*)(hF + base)     = make_float4(r0, r1, r2, r3);
            *(float4*)(hF + base + 4) = make_float4(r4, r5, r6, r7);
        } else {
            U4H8 o;
            o.h[0] = (_Float16)r0; o.h[1] = (_Float16)r1;
            o.h[2] = (_Float16)r2; o.h[3] = (_Float16)r3;
            o.h[4] = (_Float16)r4; o.h[5] = (_Float16)r5;
            o.h[6] = (_Float16)r6; o.h[7] = (_Float16)r7;
            *(uint4*)(h_out + base) = o.u;
        }
    }
}

// ---------------- decode (fused LDS transpose of hF [N,64]) ----------------
__global__ __launch_bounds__(256) void decode_kernel(float* __restrict__ y,
                                                     const float* __restrict__ ctl,
                                                     const float* __restrict__ u,
                                                     const float* __restrict__ hF,
                                                     const float* __restrict__ W1,
                                                     const float* __restrict__ b1,
                                                     const float* __restrict__ W2,
                                                     const float* __restrict__ cell_dot) {
    __shared__ float tile[64][65];
    __shared__ float4 pack[HID];
    __shared__ float w2s[HID];
    __shared__ float cds[64];
    if (threadIdx.x < HID) {
        int hh = threadIdx.x;
        pack[hh] = make_float4(W1[0 * HID + hh], W1[1 * HID + hh], W1[2 * HID + hh], b1[hh]);
        w2s[hh] = W2[hh];
        cds[hh] = cell_dot[hh];
    }
    int n0 = blockIdx.x * 64;
    int tx = threadIdx.x & 63, ty = threadIdx.x >> 6;
#pragma unroll
    for (int i = 0; i < 16; ++i) {
        int n = n0 + ty + i * 4;
        tile[ty + i * 4][tx] = (n < N_NODES) ? hF[(size_t)n * 64 + tx] : 0.f;
    }
    __syncthreads();
#pragma unroll
    for (int i = 0; i < 16; ++i) {
        int b = ty + i * 4;
        int n = n0 + tx;
        if (n < N_NODES) {
            size_t idx = (size_t)b * N_NODES + n;
            float xc = ctl[idx], xu = u[idx], xh = tile[tx][b];
            float acc = 0.f;
#pragma unroll 8
            for (int hh = 0; hh < HID; ++hh) {
                float4 p = pack[hh];
                float t = fmaf(xc, p.x, fmaf(xu, p.y, fmaf(xh, p.z, p.w)));
                t = fmaxf(t, 0.f);
                acc = fmaf(t, w2s[hh], acc);
            }
            y[idx] = acc + cds[b];
        }
    }
}

// ---------------- launch ----------------
extern "C" void kernel_launch(void* const* d_in, const int* in_sizes, int n_in,
                              void* d_out, int out_size, void* d_ws, size_t ws_size,
                              hipStream_t stream) {
    const float* ctl          = (const float*)d_in[0];
    const float* u_raw        = (const float*)d_in[1];
    const int*   cell_idx     = (const int*)d_in[2];
    const int*   edge_src     = (const int*)d_in[3];
    const int*   edge_dst     = (const int*)d_in[4];
    const float* edge_val     = (const float*)d_in[5];
    const float* g_logits     = (const float*)d_in[6];
    const float* alpha_logits = (const float*)d_in[7];
    const float* cell_emb     = (const float*)d_in[8];
    const float* W1           = (const float*)d_in[9];
    const float* b1           = (const float*)d_in[10];
    const float* W2           = (const float*)d_in[11];
    const float* b2           = (const float*)d_in[12];
    float* y = (float*)d_out;

    const int TE = in_sizes[3];   // 6 * E
    const int E  = TE / 6;
    const int NB = N_NODES * 64;  // h elements

    char* ws = (char*)d_ws;
    size_t off = 0;
    auto alloc = [&](size_t bytes) -> char* {
        char* p = ws + off;
        off += (bytes + 255) & ~(size_t)255;
        return p;
    };
    int* grp_ptr = (int*)alloc((N_NODES + 1) * sizeof(int));
    int* counts  = (int*)alloc(N_NODES * sizeof(int));
    int* blksum  = (int*)alloc(CBLK * sizeof(int));
    int* blkcnt  = (int*)alloc((size_t)NSLICE * SUBB * SLICE_SZ * sizeof(int));
    int* gcnt    = (int*)alloc((size_t)NB1 * 8 * sizeof(int));
    int* blkoff  = (int*)alloc((size_t)NB1 * 8 * sizeof(int));
    int* bbase   = (int*)alloc(16 * sizeof(int));
    const size_t MAXG = (size_t)TE / 8 + N_NODES + 8;             // padded group bound
    unsigned* eg = (unsigned*)alloc(MAXG * 8 * sizeof(unsigned)); // 32 B/group
    // DISTINCT buffers (no aliasing)
    int2* bucket    = (int2*)alloc((size_t)TE * sizeof(int2));
    _Float16* uh    = (_Float16*)alloc((size_t)NB * 2);
    _Float16* hA    = (_Float16*)alloc((size_t)NB * 2);
    _Float16* hB    = (_Float16*)alloc((size_t)NB * 2);
    float* hF       = (float*)alloc((size_t)NB * 4);
    float* u_t      = (float*)alloc((size_t)NB * sizeof(float));
    float* gsign    = (float*)alloc(8 * sizeof(float));
    float* alph     = (float*)alloc(8 * sizeof(float));
    float* cell_dot = (float*)alloc(64 * sizeof(float));

    // 1. CSR build — fully deterministic placement (replay-stable f16 steps)
    count8_kernel<<<NB1, 256, 0, stream>>>(edge_dst, gcnt, TE,
                                           (u4_t*)eg, (long long)(MAXG * 2));
    scan8_kernel<<<1, 256, 0, stream>>>(gcnt, blkoff, bbase, g_logits, alpha_logits,
                                        cell_idx, cell_emb, W2, b2,
                                        gsign, alph, cell_dot);
    bucket_kernel<<<NB1, 256, 0, stream>>>(edge_src, edge_dst, edge_val, gsign,
                                           blkoff, bbase, bucket, E, TE);
    hist2db_kernel<<<NBLK + TBLK, 256, 0, stream>>>(bucket, bbase, blkcnt,
                                                    u_raw, u_t, uh);
    colscan_kernel<<<CBLK, 256, 0, stream>>>(blkcnt, counts, blksum);
    scan2_kernel<<<CBLK, 256, 0, stream>>>(counts, blksum, grp_ptr, N_NODES);
    scatter_det_kernel<<<NBLK, 64, 0, stream>>>(bucket, bbase, grp_ptr, blkcnt, eg);

    // 2. 6 propagation steps: f16 ping-pong, fp32 final into hF
    const _Float16* hin = uh;
    for (int k = 0; k < NSTEPS; ++k) {
        _Float16* hout = (k & 1) ? hB : hA;
        step_kernel<<<(N_NODES + 3) / 4, 256, 0, stream>>>(hin, u_t, hout, hF, grp_ptr,
                                                           eg, alph, k, k == NSTEPS - 1);
        hin = hout;
    }

    // 3. decode (reads hF [N,64] directly via LDS transpose)
    decode_kernel<<<TBLK, 256, 0, stream>>>(y, ctl, u_raw, hF, W1, b1, W2, cell_dot);
}